// Round 3
// baseline (1008.991 us; speedup 1.0000x reference)
//
#include <hip/hip_runtime.h>

// ---------------------------------------------------------------------------
// GCN 2-layer inference on MI355X — round 3: bucket-partitioned edges,
// LDS-accumulated aggregation, zero global float atomics.
// F0=512, F1=16, F2=7 (padded to 8). Buckets of 64 nodes (BSH=6).
// Packing assumes n < 2^25 (here n=100000) and dstlocal < 64.
// ---------------------------------------------------------------------------

#define F0 512
#define F1 16
#define F2 7
#define BSH 6
#define BSZ 64
#define NB_MAX 1600   // >= ceil(100000/64)=1563

// Detect int64 vs int32 edge_index (odd int32 slots all zero => int64 LE).
__global__ void k_detect(const int* __restrict__ ei32, int twoE, int* __restrict__ flag) {
    int t = threadIdx.x;
    int idx = 1 + 2 * t;
    int v = (idx < twoE) ? ei32[idx] : 0;
    unsigned long long b = __ballot(v != 0);
    if (t == 0) *flag = (b == 0ULL) ? 1 : 0;
}

__global__ void k_zero(int* __restrict__ p, int n) {
    int i = blockIdx.x * blockDim.x + threadIdx.x;
    if (i < n) p[i] = 0;
}

// Pass A: per-bucket edge counts. LDS histogram per block, grouped global adds.
__global__ __launch_bounds__(256) void k_bcount(
        const int* __restrict__ ei32, const long long* __restrict__ ei64,
        const int* __restrict__ flag, int* __restrict__ bcnt,
        int E, int chunk, int NB) {
    __shared__ int h[NB_MAX];
    int t = threadIdx.x;
    for (int i = t; i < NB; i += 256) h[i] = 0;
    __syncthreads();
    bool f64 = (*flag != 0);
    int e0 = blockIdx.x * chunk;
    int e1 = e0 + chunk; if (e1 > E) e1 = E;
    for (int e = e0 + t; e < e1; e += 256) {
        int dst = f64 ? (int)ei64[(size_t)E + e] : ei32[(size_t)E + e];
        atomicAdd(&h[dst >> BSH], 1);
    }
    __syncthreads();
    for (int i = t; i < NB; i += 256) {
        int c = h[i];
        if (c) atomicAdd(&bcnt[i], c);
    }
}

// ---- exclusive scan of bcnt[NB] -> bbase[NB+1] (+cursor) -------------------
__global__ __launch_bounds__(256) void k_scanA(const int* __restrict__ cnt,
                                               int* __restrict__ bsum, int n) {
    __shared__ int s[256];
    int t = threadIdx.x, i = blockIdx.x * 256 + t;
    int v = (i < n) ? cnt[i] : 0;
    s[t] = v; __syncthreads();
    for (int off = 128; off > 0; off >>= 1) {
        if (t < off) s[t] += s[t + off];
        __syncthreads();
    }
    if (t == 0) bsum[blockIdx.x] = s[0];
}

__global__ __launch_bounds__(512) void k_scanB(int* __restrict__ bsum, int nb) {
    __shared__ int s[512];
    int t = threadIdx.x;
    int v = (t < nb) ? bsum[t] : 0;
    s[t] = v; __syncthreads();
    for (int off = 1; off < 512; off <<= 1) {
        int tv = (t >= off) ? s[t - off] : 0;
        __syncthreads();
        s[t] += tv;
        __syncthreads();
    }
    if (t < nb) bsum[t] = s[t] - v;  // exclusive
}

__global__ __launch_bounds__(256) void k_scanC(const int* __restrict__ cnt,
                                               const int* __restrict__ bsum,
                                               int* __restrict__ bbase,
                                               int* __restrict__ bcur, int n, int E) {
    __shared__ int s[256];
    int t = threadIdx.x, i = blockIdx.x * 256 + t;
    int v = (i < n) ? cnt[i] : 0;
    s[t] = v; __syncthreads();
    for (int off = 1; off < 256; off <<= 1) {
        int tv = (t >= off) ? s[t - off] : 0;
        __syncthreads();
        s[t] += tv;
        __syncthreads();
    }
    if (i < n) {
        int excl = s[t] - v + bsum[blockIdx.x];
        bbase[i] = excl;
        bcur[i] = excl;
        if (i == n - 1) bbase[n] = E;
    }
}

// Pass B: partition edges into bucket segments. Per-block LDS hist + ranks;
// one grouped global atomic per (block,bucket) to reserve ranges.
__global__ __launch_bounds__(256) void k_bscatter(
        const int* __restrict__ ei32, const long long* __restrict__ ei64,
        const int* __restrict__ flag, const float* __restrict__ w,
        int* __restrict__ bcur, int2* __restrict__ pay,
        int E, int chunk, int NB) {
    __shared__ int h[NB_MAX];
    __shared__ int base[NB_MAX];
    int t = threadIdx.x;
    for (int i = t; i < NB; i += 256) h[i] = 0;
    __syncthreads();
    bool f64 = (*flag != 0);
    int e0 = blockIdx.x * chunk;
    int e1 = e0 + chunk; if (e1 > E) e1 = E;
    for (int e = e0 + t; e < e1; e += 256) {
        int dst = f64 ? (int)ei64[(size_t)E + e] : ei32[(size_t)E + e];
        atomicAdd(&h[dst >> BSH], 1);
    }
    __syncthreads();
    for (int i = t; i < NB; i += 256) {
        int c = h[i];
        if (c) { base[i] = atomicAdd(&bcur[i], c); h[i] = 0; }
    }
    __syncthreads();
    for (int e = e0 + t; e < e1; e += 256) {   // L2-hot re-read
        int src, dst;
        if (f64) { src = (int)ei64[e]; dst = (int)ei64[(size_t)E + e]; }
        else     { src = ei32[e];      dst = ei32[(size_t)E + e]; }
        int b = dst >> BSH;
        int rank = atomicAdd(&h[b], 1);
        pay[base[b] + rank] = make_int2(src | ((dst & (BSZ - 1)) << 25),
                                        __float_as_int(w[e]));
    }
}

// Degree per bucket from payload, then dinv. No global atomics.
__global__ __launch_bounds__(256) void k_bdeg(
        const int* __restrict__ bbase, const int2* __restrict__ pay,
        float* __restrict__ dinv, int n) {
    __shared__ float dacc[BSZ];
    int b = blockIdx.x, t = threadIdx.x;
    if (t < BSZ) dacc[t] = 1.0f;   // self-loop weight
    __syncthreads();
    int p0 = bbase[b], p1 = bbase[b + 1];
    for (int p = p0 + t; p < p1; p += 256) {
        int2 pr = pay[p];
        atomicAdd(&dacc[((unsigned)pr.x) >> 25], __int_as_float(pr.y));
    }
    __syncthreads();
    if (t < BSZ) {
        int node = (b << BSH) + t;
        if (node < n) {
            float d = dacc[t];
            dinv[node] = (d > 0.f) ? rsqrtf(d) : 0.f;
        }
    }
}

// h1 = x @ W1
#define PW 516
__global__ __launch_bounds__(256) void k_gemm1(
        const float* __restrict__ x, const float* __restrict__ W1,
        float* __restrict__ h1, int n) {
    __shared__ float Wt[F1 * PW];
    int t = threadIdx.x;
    for (int idx = t; idx < F0 * F1; idx += 256) {
        int k = idx >> 4, j = idx & 15;
        Wt[j * PW + k] = W1[idx];
    }
    __syncthreads();
    int r = t >> 4, j = t & 15;
    int row = blockIdx.x * 16 + r;
    if (row >= n) return;
    const float4* xr = (const float4*)(x + (size_t)row * F0);
    const float4* wr = (const float4*)(Wt + j * PW);
    float acc = 0.f;
#pragma unroll 8
    for (int k4 = 0; k4 < F0 / 4; ++k4) {
        float4 xv = xr[k4];
        float4 wv = wr[k4];
        acc += xv.x * wv.x + xv.y * wv.y + xv.z * wv.z + xv.w * wv.w;
    }
    h1[(size_t)row * F1 + j] = acc;
}

// Layer-1 aggregate per bucket: LDS accumulators, coalesced 64B h1 gathers.
__global__ __launch_bounds__(256) void k_bagg1(
        const int* __restrict__ bbase, const int2* __restrict__ pay,
        const float* __restrict__ h1, const float* __restrict__ dinv,
        const float* __restrict__ b1, float* __restrict__ acc1, int n) {
    __shared__ float acc[BSZ * F1];   // 4 KB
    __shared__ float sdin[BSZ];
    int b = blockIdx.x, t = threadIdx.x;
    for (int i = t; i < BSZ * F1; i += 256) acc[i] = 0.f;
    if (t < BSZ) {
        int node = (b << BSH) + t;
        sdin[t] = (node < n) ? dinv[node] : 0.f;
    }
    __syncthreads();
    int p0 = bbase[b], p1 = bbase[b + 1];
    int sub = t >> 4, j = t & 15;
    for (int p = p0 + sub; p < p1; p += 16) {
        int2 pr = pay[p];                        // 16 lanes same addr -> 1 req
        unsigned lo = (unsigned)pr.x;
        int src = lo & 0x1FFFFFF;
        int dl = lo >> 25;
        float nm = dinv[src] * __int_as_float(pr.y) * sdin[dl];
        float v = nm * h1[(size_t)src * F1 + j]; // coalesced 64B line
        atomicAdd(&acc[dl * F1 + j], v);         // LDS atomic, 2-way alias=free
    }
    __syncthreads();
    for (int i = t; i < BSZ * F1; i += 256) {
        int dl = i >> 4, jj = i & 15;
        int node = (b << BSH) + dl;
        if (node < n) {
            float di = sdin[dl];
            float v = di * di * h1[(size_t)node * F1 + jj] + b1[jj] + acc[i];
            acc1[(size_t)node * F1 + jj] = fmaxf(v, 0.f);   // fused ReLU
        }
    }
}

// h2 = acc1 @ W2 (padded to 8 cols, no bias — added in bagg2).
__global__ __launch_bounds__(256) void k_layer2(
        const float* __restrict__ acc1, const float* __restrict__ W2,
        float* __restrict__ h2, int n) {
    __shared__ float sW[F1 * F2];
    int t = threadIdx.x;
    if (t < F1 * F2) sW[t] = W2[t];
    __syncthreads();
    int i = blockIdx.x * 256 + t;
    if (i >= n) return;
    const float4* a4 = (const float4*)(acc1 + (size_t)i * F1);
    float4 v0 = a4[0], v1 = a4[1], v2 = a4[2], v3 = a4[3];
    float g[F1] = {v0.x, v0.y, v0.z, v0.w, v1.x, v1.y, v1.z, v1.w,
                   v2.x, v2.y, v2.z, v2.w, v3.x, v3.y, v3.z, v3.w};
    float h[F2];
#pragma unroll
    for (int c = 0; c < F2; ++c) {
        float s = 0.f;
#pragma unroll
        for (int jj = 0; jj < F1; ++jj) s += g[jj] * sW[jj * F2 + c];
        h[c] = s;
    }
    ((float4*)(h2 + (size_t)i * 8))[0] = make_float4(h[0], h[1], h[2], h[3]);
    ((float4*)(h2 + (size_t)i * 8))[1] = make_float4(h[4], h[5], h[6], 0.f);
}

// Layer-2 aggregate per bucket + bias + log_softmax, fused.
__global__ __launch_bounds__(256) void k_bagg2(
        const int* __restrict__ bbase, const int2* __restrict__ pay,
        const float* __restrict__ h2, const float* __restrict__ dinv,
        const float* __restrict__ b2, float* __restrict__ out, int n) {
    __shared__ float acc[BSZ * 8];    // 2 KB
    __shared__ float sdin[BSZ];
    int b = blockIdx.x, t = threadIdx.x;
    for (int i = t; i < BSZ * 8; i += 256) acc[i] = 0.f;
    if (t < BSZ) {
        int node = (b << BSH) + t;
        sdin[t] = (node < n) ? dinv[node] : 0.f;
    }
    __syncthreads();
    int p0 = bbase[b], p1 = bbase[b + 1];
    int sub = t >> 3, c = t & 7;
    for (int p = p0 + sub; p < p1; p += 32) {
        int2 pr = pay[p];
        unsigned lo = (unsigned)pr.x;
        int src = lo & 0x1FFFFFF;
        int dl = lo >> 25;
        float nm = dinv[src] * __int_as_float(pr.y) * sdin[dl];
        float v = nm * h2[(size_t)src * 8 + c];
        atomicAdd(&acc[dl * 8 + c], v);
    }
    __syncthreads();
    if (t < BSZ) {
        int node = (b << BSH) + t;
        if (node < n) {
            float di = sdin[t], s2 = di * di;
            float v[F2];
            float m = -1e30f;
#pragma unroll
            for (int cc = 0; cc < F2; ++cc) {
                v[cc] = s2 * h2[(size_t)node * 8 + cc] + b2[cc] + acc[t * 8 + cc];
                m = fmaxf(m, v[cc]);
            }
            float s = 0.f;
#pragma unroll
            for (int cc = 0; cc < F2; ++cc) s += __expf(v[cc] - m);
            float ls = __logf(s) + m;
#pragma unroll
            for (int cc = 0; cc < F2; ++cc)
                out[(size_t)node * F2 + cc] = v[cc] - ls;
        }
    }
}

extern "C" void kernel_launch(void* const* d_in, const int* in_sizes, int n_in,
                              void* d_out, int out_size, void* d_ws, size_t ws_size,
                              hipStream_t stream) {
    const float* x  = (const float*)d_in[0];
    const int* ei32 = (const int*)d_in[1];
    const long long* ei64 = (const long long*)d_in[1];
    const float* w  = (const float*)d_in[2];
    const float* W1 = (const float*)d_in[3];
    const float* b1 = (const float*)d_in[4];
    const float* W2 = (const float*)d_in[5];
    const float* b2 = (const float*)d_in[6];
    float* out = (float*)d_out;

    const int n = in_sizes[0] / F0;        // 100000
    const int E = in_sizes[2];             // 3200000
    const int NB = (n + BSZ - 1) >> BSH;   // 1563
    const int snb = (NB + 255) / 256;      // scan blocks (7)

    // workspace layout (dwords)
    float* ws   = (float*)d_ws;
    float* dinv = ws;                               // n
    float* h1   = dinv + n;                         // 16n (reused as h2: 8n)
    float* acc1 = h1 + (size_t)n * F1;              // 16n
    size_t off  = (size_t)n * 33;
    off = (off + 1) & ~(size_t)1;                   // 8B align for int2
    int2* pay   = (int2*)(ws + off);                // E int2
    int* bcnt   = (int*)(pay + E);                  // NB
    int* bbase  = bcnt + NB;                        // NB+1
    int* bcur   = bbase + NB + 1;                   // NB
    int* bsum   = bcur + NB;                        // 512
    int* flag   = bsum + 512;                       // 1
    float* h2   = h1;                               // overlay (h1 dead after bagg1)

    const int B = 256;
    const int PGRID = 512;
    const int chunk = (E + PGRID - 1) / PGRID;      // 6250

    k_detect<<<1, 64, 0, stream>>>(ei32, 2 * E, flag);
    k_zero<<<(NB + B - 1) / B, B, 0, stream>>>(bcnt, NB);
    k_bcount<<<PGRID, B, 0, stream>>>(ei32, ei64, flag, bcnt, E, chunk, NB);
    k_scanA<<<snb, B, 0, stream>>>(bcnt, bsum, NB);
    k_scanB<<<1, 512, 0, stream>>>(bsum, snb);
    k_scanC<<<snb, B, 0, stream>>>(bcnt, bsum, bbase, bcur, NB, E);
    k_bscatter<<<PGRID, B, 0, stream>>>(ei32, ei64, flag, w, bcur, pay, E, chunk, NB);
    k_bdeg<<<NB, B, 0, stream>>>(bbase, pay, dinv, n);
    k_gemm1<<<(n + 15) / 16, B, 0, stream>>>(x, W1, h1, n);
    k_bagg1<<<NB, B, 0, stream>>>(bbase, pay, h1, dinv, b1, acc1, n);
    k_layer2<<<(n + B - 1) / B, B, 0, stream>>>(acc1, W2, h2, n);
    k_bagg2<<<NB, B, 0, stream>>>(bbase, pay, h2, dinv, b2, out, n);
}